// Round 5
// baseline (253.995 us; speedup 1.0000x reference)
//
#include <hip/hip_runtime.h>
#include <float.h>
#include <limits.h>

#define MEMN 65536
#define WD 128
#define KSEL 8
#define RD 9
#define BD 32
#define IND 512
#define IFACE 266
#define XI_STRIDE 272   // pad 266 -> 272 floats (1088B, 16B-aligned rows)

#define NCHUNK 64
#define ROWS_PER_CHUNK 1024              // per block; 4 waves x 256 rows
#define CAND_SCAN (NCHUNK * KSEL)        // 512
#define CAND_REAL (CAND_SCAN + RD)       // 521
#define CAND_PER_BATCH 528               // padded

typedef float fvec4 __attribute__((ext_vector_type(4)));

// Sorted ascending (val, idx) top-8 insert; fully unrolled -> registers only.
#define TOP8_INSERT(bv, bi, vin, iin)                                  \
  { float _v = (vin); int _i = (iin);                                  \
    _Pragma("unroll")                                                  \
    for (int _j = 0; _j < 8; ++_j) {                                   \
      bool _b = (_v < bv[_j]) || (_v == bv[_j] && _i < bi[_j]);        \
      float _tv = bv[_j]; int _ti = bi[_j];                            \
      bv[_j] = _b ? _v : _tv;  bi[_j] = _b ? _i : _ti;                 \
      _v = _b ? _tv : _v;      _i = _b ? _ti : _i;                     \
    } }

// Fused: xi GEMM (2-way split-K in LDS) -> gates -> new_rv -> fixup scores.
__global__ __launch_bounds__(544)
void head_kernel(const float* __restrict__ x, const float* __restrict__ Wif,
                 const float* __restrict__ bif,
                 const float* __restrict__ read_weights, const float* __restrict__ read_vectors,
                 const int* __restrict__ rpos,
                 float* __restrict__ xi, float* __restrict__ new_rv,
                 float* __restrict__ cand_val, int* __restrict__ cand_idx) {
  const int b = blockIdx.x, t = threadIdx.x;  // 544 = 2 halves x 272 cols
  __shared__ float part[2][272];
  __shared__ float xiS[IFACE];
  __shared__ float wwS[RD];
  __shared__ float nvS[RD][WD];

  const int c = t % 272, h = t / 272;
  if (c < IFACE) {
    const float* xr = x + b * IND + h * 256;
    const float* wp = Wif + (size_t)(h * 256) * IFACE + c;
    float a0 = 0.f, a1 = 0.f, a2 = 0.f, a3 = 0.f;
    #pragma unroll 4
    for (int k = 0; k < 256; k += 4) {
      a0 += xr[k]     * wp[(k)     * IFACE];
      a1 += xr[k + 1] * wp[(k + 1) * IFACE];
      a2 += xr[k + 2] * wp[(k + 2) * IFACE];
      a3 += xr[k + 3] * wp[(k + 3) * IFACE];
    }
    part[h][c] = (a0 + a1) + (a2 + a3);
  }
  __syncthreads();

  if (t < IFACE) {
    float acc = bif[t] + part[0][t] + part[1][t];
    xiS[t] = acc;
    xi[b * XI_STRIDE + t] = acc;   // scan reads query cols [0,128)
  }
  __syncthreads();

  if (t < RD) {
    float g  = 1.f / (1.f + __expf(-xiS[2 * WD + t]));
    float wg = 1.f / (1.f + __expf(-xiS[IFACE - 1]));
    wwS[t] = wg * (g * read_weights[b * RD + t] + (1.f - g));
  }
  __syncthreads();

  if (t < WD) {
    const float wv = xiS[WD + t];
    #pragma unroll
    for (int r = 0; r < RD; ++r) {
      float nv = read_vectors[(b * RD + r) * WD + t] + wwS[r] * wv;
      nvS[r][t] = nv;
      new_rv[(b * RD + r) * WD + t] = nv;
    }
  }
  __syncthreads();

  if (t < 64) {
    const int lane = t;
    const float q0 = xiS[lane * 2], q1 = xiS[lane * 2 + 1];
    for (int r = 0; r < RD; ++r) {
      float m0 = nvS[r][lane * 2], m1 = nvS[r][lane * 2 + 1];
      float s = m0 * (m0 - 2.f * q0) + m1 * (m1 - 2.f * q1);
      #pragma unroll
      for (int off = 32; off; off >>= 1) s += __shfl_xor(s, off);
      if (lane == 0) {
        int p = rpos[b * RD + r];
        bool dup = false;
        for (int r2 = r + 1; r2 < RD; ++r2) dup |= (rpos[b * RD + r2] == p);
        int slot = b * CAND_PER_BATCH + CAND_SCAN + r;
        cand_val[slot] = dup ? FLT_MAX : s;   // numpy scatter: last duplicate wins
        cand_idx[slot] = dup ? INT_MAX : p;
      }
    }
  }
}

// Copy-identical addressing: lane l reads byte l*16 of a 1KB row-pair.
// Each wave iter: 4 loads x 1KB contiguous = 8 rows; lanes 0-31 hold even row,
// 32-63 odd row; 4 independent 5-step butterfly reduces; lanes 0/32 keep top8.
__global__ __launch_bounds__(256)
void scan_kernel(const float* __restrict__ memory, const float* __restrict__ xi,
                 const int* __restrict__ rpos,
                 float* __restrict__ cand_val, int* __restrict__ cand_idx) {
  const int b = blockIdx.y, chunk = blockIdx.x;
  const int t = threadIdx.x;
  const int w = t >> 6, l = t & 63;
  const int half = l >> 5;                       // even/odd row of the pair
  const int waveBase = chunk * ROWS_PER_CHUNK + w * (ROWS_PER_CHUNK / 4);

  int rp[RD];
  #pragma unroll
  for (int r = 0; r < RD; ++r) rp[r] = rpos[b * RD + r];

  const fvec4 q = *(const fvec4*)(xi + b * XI_STRIDE + (l & 31) * 4);
  const fvec4 tq = q * 2.f;

  float bv[8]; int bi[8];
  #pragma unroll
  for (int j = 0; j < 8; ++j) { bv[j] = FLT_MAX; bi[j] = INT_MAX; }

  const char* base = (const char*)memory
                   + ((size_t)b * MEMN + waveBase) * (WD * 4) + (size_t)l * 16;

  #pragma unroll 2
  for (int i = 0; i < 32; ++i) {                 // 8 rows per iter, 256 rows total
    const char* p = base + (size_t)i * 4096;
    const fvec4 m0 = *(const fvec4*)(p);
    const fvec4 m1 = *(const fvec4*)(p + 1024);
    const fvec4 m2 = *(const fvec4*)(p + 2048);
    const fvec4 m3 = *(const fvec4*)(p + 3072);

    float s0 = m0.x*(m0.x-tq.x) + m0.y*(m0.y-tq.y) + m0.z*(m0.z-tq.z) + m0.w*(m0.w-tq.w);
    float s1 = m1.x*(m1.x-tq.x) + m1.y*(m1.y-tq.y) + m1.z*(m1.z-tq.z) + m1.w*(m1.w-tq.w);
    float s2 = m2.x*(m2.x-tq.x) + m2.y*(m2.y-tq.y) + m2.z*(m2.z-tq.z) + m2.w*(m2.w-tq.w);
    float s3 = m3.x*(m3.x-tq.x) + m3.y*(m3.y-tq.y) + m3.z*(m3.z-tq.z) + m3.w*(m3.w-tq.w);

    #pragma unroll
    for (int off = 1; off < 32; off <<= 1) {     // 4 independent 32-lane reduces
      s0 += __shfl_xor(s0, off);
      s1 += __shfl_xor(s1, off);
      s2 += __shfl_xor(s2, off);
      s3 += __shfl_xor(s3, off);
    }

    if ((l & 31) == 0) {                         // lanes 0 (even row) & 32 (odd row)
      const int mr = waveBase + i * 8 + half;
      bool k0 = false, k1 = false, k2 = false, k3 = false;
      #pragma unroll
      for (int r = 0; r < RD; ++r) {
        k0 |= (mr     == rp[r]); k1 |= (mr + 2 == rp[r]);
        k2 |= (mr + 4 == rp[r]); k3 |= (mr + 6 == rp[r]);
      }
      if (!k0 && (s0 < bv[7] || (s0 == bv[7] && mr     < bi[7]))) TOP8_INSERT(bv, bi, s0, mr);
      if (!k1 && (s1 < bv[7] || (s1 == bv[7] && mr + 2 < bi[7]))) TOP8_INSERT(bv, bi, s1, mr + 2);
      if (!k2 && (s2 < bv[7] || (s2 == bv[7] && mr + 4 < bi[7]))) TOP8_INSERT(bv, bi, s2, mr + 4);
      if (!k3 && (s3 < bv[7] || (s3 == bv[7] && mr + 6 < bi[7]))) TOP8_INSERT(bv, bi, s3, mr + 6);
    }
  }

  // Merge 8 top8 sets (4 waves x 2 half-lanes) -> chunk top8.
  __shared__ float lv[8][8];
  __shared__ int   li[8][8];
  if ((l & 31) == 0) {
    #pragma unroll
    for (int j = 0; j < 8; ++j) { lv[w * 2 + half][j] = bv[j]; li[w * 2 + half][j] = bi[j]; }
  }
  __syncthreads();
  for (int s = 4; s >= 1; s >>= 1) {
    if (t < s) {
      float mv[8]; int mi[8];
      #pragma unroll
      for (int j = 0; j < 8; ++j) { mv[j] = lv[t][j]; mi[j] = li[t][j]; }
      #pragma unroll
      for (int j = 0; j < 8; ++j) {
        float v = lv[t + s][j]; int i = li[t + s][j];
        if (v < mv[7] || (v == mv[7] && i < mi[7])) TOP8_INSERT(mv, mi, v, i);
      }
      #pragma unroll
      for (int j = 0; j < 8; ++j) { lv[t][j] = mv[j]; li[t][j] = mi[j]; }
    }
    __syncthreads();
  }
  if (t < 8) {
    cand_val[b * CAND_PER_BATCH + chunk * 8 + t] = lv[0][t];
    cand_idx[b * CAND_PER_BATCH + chunk * 8 + t] = li[0][t];
  }
}

__global__ __launch_bounds__(128)
void final_kernel(const float* __restrict__ cand_val, const int* __restrict__ cand_idx,
                  const float* __restrict__ memory, const float* __restrict__ new_rv,
                  const int* __restrict__ rpos, float* __restrict__ out) {
  const int b = blockIdx.x, t = threadIdx.x;  // 128
  __shared__ float lv[128][8];
  __shared__ int   li[128][8];
  __shared__ int   posS[KSEL], srcS[KSEL];

  float bv[8]; int bi[8];
  #pragma unroll
  for (int j = 0; j < 8; ++j) { bv[j] = FLT_MAX; bi[j] = INT_MAX; }

  for (int e = t; e < CAND_REAL; e += 128) {
    float v = cand_val[b * CAND_PER_BATCH + e];
    int   i = cand_idx[b * CAND_PER_BATCH + e];
    if (v < bv[7] || (v == bv[7] && i < bi[7])) TOP8_INSERT(bv, bi, v, i);
  }
  #pragma unroll
  for (int j = 0; j < 8; ++j) { lv[t][j] = bv[j]; li[t][j] = bi[j]; }
  __syncthreads();

  for (int stride = 64; stride >= 1; stride >>= 1) {
    if (t < stride) {
      #pragma unroll
      for (int j = 0; j < 8; ++j) {
        float v = lv[t + stride][j]; int i = li[t + stride][j];
        if (v < bv[7] || (v == bv[7] && i < bi[7])) TOP8_INSERT(bv, bi, v, i);
      }
      #pragma unroll
      for (int j = 0; j < 8; ++j) { lv[t][j] = bv[j]; li[t][j] = bi[j]; }
    }
    __syncthreads();
  }

  if (t < KSEL) {
    int p = li[0][t];
    int src = -1;
    for (int r = 0; r < RD; ++r) if (rpos[b * RD + r] == p) src = r;  // last wins
    posS[t] = p; srcS[t] = src;
  }
  __syncthreads();

  for (int e = t; e < KSEL * WD; e += 128) {
    int k = e >> 7, wv = e & 127;
    int p = posS[k], src = srcS[k];
    float val = (src >= 0) ? new_rv[(b * RD + src) * WD + wv]
                           : memory[((size_t)b * MEMN + p) * WD + wv];
    out[b * KSEL * WD + e] = val;
  }
}

extern "C" void kernel_launch(void* const* d_in, const int* in_sizes, int n_in,
                              void* d_out, int out_size, void* d_ws, size_t ws_size,
                              hipStream_t stream) {
  const float* x      = (const float*)d_in[0];
  const float* Wif    = (const float*)d_in[1];
  const float* bif    = (const float*)d_in[2];
  const float* memory = (const float*)d_in[3];
  const float* rw     = (const float*)d_in[4];
  const float* rv     = (const float*)d_in[5];
  const int*   rpos   = (const int*)d_in[6];
  // d_in[7] (last_used_mem) unused: reference drops that gathered row.

  float* ws       = (float*)d_ws;
  float* xi       = ws;                                   // BD*XI_STRIDE floats
  float* new_rv   = xi + BD * XI_STRIDE;                  // BD*RD*WD
  float* cand_val = new_rv + BD * RD * WD;                // BD*CAND_PER_BATCH
  int*   cand_idx = (int*)(cand_val + BD * CAND_PER_BATCH);
  float* out      = (float*)d_out;

  head_kernel<<<dim3(BD), dim3(544), 0, stream>>>(x, Wif, bif, rw, rv, rpos,
                                                  xi, new_rv, cand_val, cand_idx);
  scan_kernel<<<dim3(NCHUNK, BD), dim3(256), 0, stream>>>(memory, xi, rpos, cand_val, cand_idx);
  final_kernel<<<dim3(BD), dim3(128), 0, stream>>>(cand_val, cand_idx, memory, new_rv, rpos, out);
}

// Round 6
// 240.725 us; speedup vs baseline: 1.0551x; 1.0551x over previous
//
#include <hip/hip_runtime.h>
#include <float.h>
#include <limits.h>

#define MEMN 65536
#define WD 128
#define KSEL 8
#define RD 9
#define BD 32
#define IND 512
#define IFACE 266
#define XI_STRIDE 272   // pad 266 -> 272 floats (1088B, 16B-aligned rows)

#define KSEG 8
#define KSEG_LEN (IND / KSEG)            // 64

#define NCHUNK 64
#define ROWS_PER_CHUNK 1024              // rows per block (striped tiles of 64)
#define CAND_SCAN (NCHUNK * KSEL)        // 512
#define CAND_REAL (CAND_SCAN + RD)       // 521
#define CAND_PER_BATCH 528               // padded

typedef float fvec4 __attribute__((ext_vector_type(4)));

// Sorted ascending (val, idx) top-8 insert; fully unrolled -> registers only.
#define TOP8_INSERT(bv, bi, vin, iin)                                  \
  { float _v = (vin); int _i = (iin);                                  \
    _Pragma("unroll")                                                  \
    for (int _j = 0; _j < 8; ++_j) {                                   \
      bool _b = (_v < bv[_j]) || (_v == bv[_j] && _i < bi[_j]);        \
      float _tv = bv[_j]; int _ti = bi[_j];                            \
      bv[_j] = _b ? _v : _tv;  bi[_j] = _b ? _i : _ti;                 \
      _v = _b ? _tv : _v;      _i = _b ? _ti : _i;                     \
    } }

__device__ __forceinline__ fvec4 ntload(const void* p) {
  return __builtin_nontemporal_load((const fvec4*)p);
}

// Split-K partial GEMM: block (b, seg) computes 64-deep partials for all 266 cols.
__global__ __launch_bounds__(288)
void xi_part_kernel(const float* __restrict__ x, const float* __restrict__ Wif,
                    float* __restrict__ xi_part) {
  const int b = blockIdx.x, seg = blockIdx.y, c = threadIdx.x;
  if (c >= IFACE) return;
  const float* xr = x + b * IND + seg * KSEG_LEN;       // block-uniform -> s_loads
  const float* wp = Wif + (size_t)(seg * KSEG_LEN) * IFACE + c;
  float a0 = 0.f, a1 = 0.f, a2 = 0.f, a3 = 0.f;
  #pragma unroll
  for (int k = 0; k < KSEG_LEN; k += 4) {
    a0 += xr[k]     * wp[(size_t)k * IFACE];
    a1 += xr[k + 1] * wp[(size_t)(k + 1) * IFACE];
    a2 += xr[k + 2] * wp[(size_t)(k + 2) * IFACE];
    a3 += xr[k + 3] * wp[(size_t)(k + 3) * IFACE];
  }
  xi_part[(b * KSEG + seg) * XI_STRIDE + c] = (a0 + a1) + (a2 + a3);
}

// Fused: xi reduce (+bias) -> gates/new_rv -> fixup candidate scores.
__global__ __launch_bounds__(320)
void head_kernel(const float* __restrict__ xi_part, const float* __restrict__ bif,
                 const float* __restrict__ read_weights, const float* __restrict__ read_vectors,
                 const int* __restrict__ rpos,
                 float* __restrict__ xi, float* __restrict__ new_rv,
                 float* __restrict__ cand_val, int* __restrict__ cand_idx) {
  const int b = blockIdx.x, t = threadIdx.x;  // 320
  __shared__ float xiS[IFACE];
  __shared__ float wwS[RD];
  __shared__ float nvS[RD][WD];

  // phase 0: reduce split-K partials
  if (t < IFACE) {
    float acc = bif[t];
    #pragma unroll
    for (int s = 0; s < KSEG; ++s)
      acc += xi_part[(b * KSEG + s) * XI_STRIDE + t];
    xiS[t] = acc;
    xi[b * XI_STRIDE + t] = acc;   // scan reads query cols [0,128)
  }
  __syncthreads();

  // phase 1: write weights
  if (t < RD) {
    float g  = 1.f / (1.f + __expf(-xiS[2 * WD + t]));
    float wg = 1.f / (1.f + __expf(-xiS[IFACE - 1]));
    wwS[t] = wg * (g * read_weights[b * RD + t] + (1.f - g));
  }
  __syncthreads();

  // phase 2: new_rv
  if (t < WD) {
    const float wv = xiS[WD + t];
    #pragma unroll
    for (int r = 0; r < RD; ++r) {
      float nv = read_vectors[(b * RD + r) * WD + t] + wwS[r] * wv;
      nvS[r][t] = nv;
      new_rv[(b * RD + r) * WD + t] = nv;
    }
  }
  __syncthreads();

  // phase 3: fixup scores for the 9 scattered rows (wave 0 only)
  if (t < 64) {
    const int lane = t;
    const float q0 = xiS[lane * 2], q1 = xiS[lane * 2 + 1];
    for (int r = 0; r < RD; ++r) {
      float m0 = nvS[r][lane * 2], m1 = nvS[r][lane * 2 + 1];
      float s = m0 * (m0 - 2.f * q0) + m1 * (m1 - 2.f * q1);
      #pragma unroll
      for (int off = 32; off; off >>= 1) s += __shfl_xor(s, off);
      if (lane == 0) {
        int p = rpos[b * RD + r];
        bool dup = false;
        for (int r2 = r + 1; r2 < RD; ++r2) dup |= (rpos[b * RD + r2] == p);
        int slot = b * CAND_PER_BATCH + CAND_SCAN + r;
        cand_val[slot] = dup ? FLT_MAX : s;   // numpy scatter: last duplicate wins
        cand_idx[slot] = dup ? INT_MAX : p;
      }
    }
  }
}

// 256 threads = 4 waves; wave handles 16 rows/iter via 4-lane groups.
// Lane ln of a group owns row bytes ln*16 + j*64 (j=0..7) -> 8 nt float4 loads.
// STRIPED tile ownership: block `chunk` handles 64-row tile (i*NCHUNK + chunk)
// at iteration i, so concurrently-active addresses across the 64 blocks of a
// batch form one dense contiguous 2MB window (even HBM channel interleave),
// instead of a 512KB-strided comb.
__global__ __launch_bounds__(256)
void scan_kernel(const float* __restrict__ memory, const float* __restrict__ xi,
                 const int* __restrict__ rpos,
                 float* __restrict__ cand_val, int* __restrict__ cand_idx) {
  const int b = blockIdx.y, chunk = blockIdx.x;
  const int t = threadIdx.x;
  const int w = t >> 6, l = t & 63, g = l >> 2, ln = l & 3;

  int rp[RD];
  #pragma unroll
  for (int r = 0; r < RD; ++r) rp[r] = rpos[b * RD + r];

  // 2*query, this lane's 32 columns (8 vec4s)
  fvec4 tq[8];
  #pragma unroll
  for (int j = 0; j < 8; ++j) {
    fvec4 q = *(const fvec4*)(xi + b * XI_STRIDE + j * 16 + ln * 4);
    tq[j] = q * 2.f;
  }

  float bv[8]; int bi[8];
  #pragma unroll
  for (int j = 0; j < 8; ++j) { bv[j] = FLT_MAX; bi[j] = INT_MAX; }

  const char* memB = (const char*)memory + (size_t)b * MEMN * (WD * 4);

  #pragma unroll 2
  for (int i = 0; i < ROWS_PER_CHUNK / 64; ++i) {       // 16 striped tiles
    const int m = (i * NCHUNK + chunk) * 64 + w * 16 + g;
    const char* p = memB + (size_t)m * (WD * 4) + ln * 16;
    float sA = 0.f, sB = 0.f;
    #pragma unroll
    for (int j = 0; j < 8; j += 2) {
      fvec4 m0 = ntload(p + j * 64);
      fvec4 m1 = ntload(p + (j + 1) * 64);
      sA += m0.x * (m0.x - tq[j].x) + m0.y * (m0.y - tq[j].y)
          + m0.z * (m0.z - tq[j].z) + m0.w * (m0.w - tq[j].w);
      sB += m1.x * (m1.x - tq[j + 1].x) + m1.y * (m1.y - tq[j + 1].y)
          + m1.z * (m1.z - tq[j + 1].z) + m1.w * (m1.w - tq[j + 1].w);
    }
    float s = sA + sB;
    s += __shfl_xor(s, 1);
    s += __shfl_xor(s, 2);        // lanes ln==0 hold full row score
    if (ln == 0) {
      bool skip = false;
      #pragma unroll
      for (int r = 0; r < RD; ++r) skip |= (m == rp[r]);  // scattered rows: stale
      if (!skip && (s < bv[7] || (s == bv[7] && m < bi[7]))) TOP8_INSERT(bv, bi, s, m);
    }
  }

  // Merge 64 group-top8s (4 waves x 16 groups) -> chunk top8.
  __shared__ float lv[64][8];
  __shared__ int   li[64][8];
  if (ln == 0) {
    #pragma unroll
    for (int j = 0; j < 8; ++j) { lv[w * 16 + g][j] = bv[j]; li[w * 16 + g][j] = bi[j]; }
  }
  __syncthreads();
  for (int s = 32; s >= 1; s >>= 1) {
    if (t < s) {
      float mv[8]; int mi[8];
      #pragma unroll
      for (int j = 0; j < 8; ++j) { mv[j] = lv[t][j]; mi[j] = li[t][j]; }
      #pragma unroll
      for (int j = 0; j < 8; ++j) {
        float v = lv[t + s][j]; int i = li[t + s][j];
        if (v < mv[7] || (v == mv[7] && i < mi[7])) TOP8_INSERT(mv, mi, v, i);
      }
      #pragma unroll
      for (int j = 0; j < 8; ++j) { lv[t][j] = mv[j]; li[t][j] = mi[j]; }
    }
    __syncthreads();
  }
  if (t < 8) {
    cand_val[b * CAND_PER_BATCH + chunk * 8 + t] = lv[0][t];
    cand_idx[b * CAND_PER_BATCH + chunk * 8 + t] = li[0][t];
  }
}

__global__ __launch_bounds__(128)
void final_kernel(const float* __restrict__ cand_val, const int* __restrict__ cand_idx,
                  const float* __restrict__ memory, const float* __restrict__ new_rv,
                  const int* __restrict__ rpos, float* __restrict__ out) {
  const int b = blockIdx.x, t = threadIdx.x;  // 128
  __shared__ float lv[128][8];
  __shared__ int   li[128][8];
  __shared__ int   posS[KSEL], srcS[KSEL];

  float bv[8]; int bi[8];
  #pragma unroll
  for (int j = 0; j < 8; ++j) { bv[j] = FLT_MAX; bi[j] = INT_MAX; }

  for (int e = t; e < CAND_REAL; e += 128) {
    float v = cand_val[b * CAND_PER_BATCH + e];
    int   i = cand_idx[b * CAND_PER_BATCH + e];
    if (v < bv[7] || (v == bv[7] && i < bi[7])) TOP8_INSERT(bv, bi, v, i);
  }
  #pragma unroll
  for (int j = 0; j < 8; ++j) { lv[t][j] = bv[j]; li[t][j] = bi[j]; }
  __syncthreads();

  for (int stride = 64; stride >= 1; stride >>= 1) {
    if (t < stride) {
      #pragma unroll
      for (int j = 0; j < 8; ++j) {
        float v = lv[t + stride][j]; int i = li[t + stride][j];
        if (v < bv[7] || (v == bv[7] && i < bi[7])) TOP8_INSERT(bv, bi, v, i);
      }
      #pragma unroll
      for (int j = 0; j < 8; ++j) { lv[t][j] = bv[j]; li[t][j] = bi[j]; }
    }
    __syncthreads();
  }

  if (t < KSEL) {
    int p = li[0][t];
    int src = -1;
    for (int r = 0; r < RD; ++r) if (rpos[b * RD + r] == p) src = r;  // last wins
    posS[t] = p; srcS[t] = src;
  }
  __syncthreads();

  for (int e = t; e < KSEL * WD; e += 128) {
    int k = e >> 7, wv = e & 127;
    int p = posS[k], src = srcS[k];
    float val = (src >= 0) ? new_rv[(b * RD + src) * WD + wv]
                           : memory[((size_t)b * MEMN + p) * WD + wv];
    out[b * KSEL * WD + e] = val;
  }
}

extern "C" void kernel_launch(void* const* d_in, const int* in_sizes, int n_in,
                              void* d_out, int out_size, void* d_ws, size_t ws_size,
                              hipStream_t stream) {
  const float* x      = (const float*)d_in[0];
  const float* Wif    = (const float*)d_in[1];
  const float* bif    = (const float*)d_in[2];
  const float* memory = (const float*)d_in[3];
  const float* rw     = (const float*)d_in[4];
  const float* rv     = (const float*)d_in[5];
  const int*   rpos   = (const int*)d_in[6];
  // d_in[7] (last_used_mem) unused: reference drops that gathered row.

  float* ws       = (float*)d_ws;
  float* xi_part  = ws;                                   // BD*KSEG*XI_STRIDE floats
  float* xi       = xi_part + BD * KSEG * XI_STRIDE;      // BD*XI_STRIDE
  float* new_rv   = xi + BD * XI_STRIDE;                  // BD*RD*WD
  float* cand_val = new_rv + BD * RD * WD;                // BD*CAND_PER_BATCH
  int*   cand_idx = (int*)(cand_val + BD * CAND_PER_BATCH);
  float* out      = (float*)d_out;

  xi_part_kernel<<<dim3(BD, KSEG), dim3(288), 0, stream>>>(x, Wif, xi_part);
  head_kernel<<<dim3(BD), dim3(320), 0, stream>>>(xi_part, bif, rw, rv, rpos,
                                                  xi, new_rv, cand_val, cand_idx);
  scan_kernel<<<dim3(NCHUNK, BD), dim3(256), 0, stream>>>(memory, xi, rpos, cand_val, cand_idx);
  final_kernel<<<dim3(BD), dim3(128), 0, stream>>>(cand_val, cand_idx, memory, new_rv, rpos, out);
}

// Round 7
// 227.763 us; speedup vs baseline: 1.1152x; 1.0569x over previous
//
#include <hip/hip_runtime.h>
#include <float.h>
#include <limits.h>

#define MEMN 65536
#define WD 128
#define KSEL 8
#define RD 9
#define BD 32
#define IND 512
#define IFACE 266
#define XI_STRIDE 272   // pad 266 -> 272 floats (1088B, 16B-aligned rows)

#define KSEG 8
#define KSEG_LEN (IND / KSEG)            // 64

#define NCHUNK 64
#define ROWS_PER_CHUNK 1024              // per block; 4 waves x 256 rows
#define CAND_SCAN (NCHUNK * KSEL)        // 512
#define CAND_REAL (CAND_SCAN + RD)       // 521
#define CAND_PER_BATCH 528               // padded

typedef float fvec4 __attribute__((ext_vector_type(4)));

// Sorted ascending (val, idx) top-8 insert; fully unrolled -> registers only.
#define TOP8_INSERT(bv, bi, vin, iin)                                  \
  { float _v = (vin); int _i = (iin);                                  \
    _Pragma("unroll")                                                  \
    for (int _j = 0; _j < 8; ++_j) {                                   \
      bool _b = (_v < bv[_j]) || (_v == bv[_j] && _i < bi[_j]);        \
      float _tv = bv[_j]; int _ti = bi[_j];                            \
      bv[_j] = _b ? _v : _tv;  bi[_j] = _b ? _i : _ti;                 \
      _v = _b ? _tv : _v;      _i = _b ? _ti : _i;                     \
    } }

__device__ __forceinline__ fvec4 ntload(const void* p) {
  return __builtin_nontemporal_load((const fvec4*)p);
}

// Split-K partial GEMM: block (b, seg) computes 64-deep partials for all 266 cols.
__global__ __launch_bounds__(288)
void xi_part_kernel(const float* __restrict__ x, const float* __restrict__ Wif,
                    float* __restrict__ xi_part) {
  const int b = blockIdx.x, seg = blockIdx.y, c = threadIdx.x;
  if (c >= IFACE) return;
  const float* xr = x + b * IND + seg * KSEG_LEN;       // block-uniform -> s_loads
  const float* wp = Wif + (size_t)(seg * KSEG_LEN) * IFACE + c;
  float a0 = 0.f, a1 = 0.f, a2 = 0.f, a3 = 0.f;
  #pragma unroll
  for (int k = 0; k < KSEG_LEN; k += 4) {
    a0 += xr[k]     * wp[(size_t)k * IFACE];
    a1 += xr[k + 1] * wp[(size_t)(k + 1) * IFACE];
    a2 += xr[k + 2] * wp[(size_t)(k + 2) * IFACE];
    a3 += xr[k + 3] * wp[(size_t)(k + 3) * IFACE];
  }
  xi_part[(b * KSEG + seg) * XI_STRIDE + c] = (a0 + a1) + (a2 + a3);
}

// Fused: xi reduce (+bias) -> gates/new_rv -> fixup candidate scores.
__global__ __launch_bounds__(320)
void head_kernel(const float* __restrict__ xi_part, const float* __restrict__ bif,
                 const float* __restrict__ read_weights, const float* __restrict__ read_vectors,
                 const int* __restrict__ rpos,
                 float* __restrict__ xi, float* __restrict__ new_rv,
                 float* __restrict__ cand_val, int* __restrict__ cand_idx) {
  const int b = blockIdx.x, t = threadIdx.x;  // 320
  __shared__ float xiS[IFACE];
  __shared__ float wwS[RD];
  __shared__ float nvS[RD][WD];

  // phase 0: reduce split-K partials
  if (t < IFACE) {
    float acc = bif[t];
    #pragma unroll
    for (int s = 0; s < KSEG; ++s)
      acc += xi_part[(b * KSEG + s) * XI_STRIDE + t];
    xiS[t] = acc;
    xi[b * XI_STRIDE + t] = acc;   // scan reads query cols [0,128)
  }
  __syncthreads();

  // phase 1: write weights
  if (t < RD) {
    float g  = 1.f / (1.f + __expf(-xiS[2 * WD + t]));
    float wg = 1.f / (1.f + __expf(-xiS[IFACE - 1]));
    wwS[t] = wg * (g * read_weights[b * RD + t] + (1.f - g));
  }
  __syncthreads();

  // phase 2: new_rv
  if (t < WD) {
    const float wv = xiS[WD + t];
    #pragma unroll
    for (int r = 0; r < RD; ++r) {
      float nv = read_vectors[(b * RD + r) * WD + t] + wwS[r] * wv;
      nvS[r][t] = nv;
      new_rv[(b * RD + r) * WD + t] = nv;
    }
  }
  __syncthreads();

  // phase 3: fixup scores for the 9 scattered rows (wave 0 only)
  if (t < 64) {
    const int lane = t;
    const float q0 = xiS[lane * 2], q1 = xiS[lane * 2 + 1];
    for (int r = 0; r < RD; ++r) {
      float m0 = nvS[r][lane * 2], m1 = nvS[r][lane * 2 + 1];
      float s = m0 * (m0 - 2.f * q0) + m1 * (m1 - 2.f * q1);
      #pragma unroll
      for (int off = 32; off; off >>= 1) s += __shfl_xor(s, off);
      if (lane == 0) {
        int p = rpos[b * RD + r];
        bool dup = false;
        for (int r2 = r + 1; r2 < RD; ++r2) dup |= (rpos[b * RD + r2] == p);
        int slot = b * CAND_PER_BATCH + CAND_SCAN + r;
        cand_val[slot] = dup ? FLT_MAX : s;   // numpy scatter: last duplicate wins
        cand_idx[slot] = dup ? INT_MAX : p;
      }
    }
  }
}

// 256 threads = 4 waves; wave handles 8 rows/iter via 8-lane groups.
// Lane ln of group g reads bytes ln*16 + j*128 (j=0..3) of row (base + i*8 + g):
// every wave load instruction covers 8 FULL 128B cache lines (aligned), vs the
// previous 16 half-lines -> halves the TCC line-request rate at equal bytes.
__global__ __launch_bounds__(256)
void scan_kernel(const float* __restrict__ memory, const float* __restrict__ xi,
                 const int* __restrict__ rpos,
                 float* __restrict__ cand_val, int* __restrict__ cand_idx) {
  const int b = blockIdx.y, chunk = blockIdx.x;
  const int t = threadIdx.x;
  const int w = t >> 6, l = t & 63, g = l >> 3, ln = l & 7;
  const int waveBase = chunk * ROWS_PER_CHUNK + w * (ROWS_PER_CHUNK / 4);

  int rp[RD];
  #pragma unroll
  for (int r = 0; r < RD; ++r) rp[r] = rpos[b * RD + r];

  // 2*query, this lane's 16 columns (4 vec4s): cols ln*4 + j*32
  fvec4 tq[4];
  #pragma unroll
  for (int j = 0; j < 4; ++j) {
    fvec4 q = *(const fvec4*)(xi + b * XI_STRIDE + j * 32 + ln * 4);
    tq[j] = q * 2.f;
  }

  float bv[8]; int bi[8];
  #pragma unroll
  for (int j = 0; j < 8; ++j) { bv[j] = FLT_MAX; bi[j] = INT_MAX; }

  const char* base = (const char*)memory + (size_t)b * MEMN * (WD * 4)
                   + (size_t)(waveBase + g) * (WD * 4) + ln * 16;

  #pragma unroll 2
  for (int i = 0; i < ROWS_PER_CHUNK / 4 / 8; ++i) {    // 32 iters, 8 rows each
    const char* p = base + (size_t)i * 4096;
    const fvec4 m0 = ntload(p);
    const fvec4 m1 = ntload(p + 128);
    const fvec4 m2 = ntload(p + 256);
    const fvec4 m3 = ntload(p + 384);

    float sA = m0.x*(m0.x-tq[0].x) + m0.y*(m0.y-tq[0].y)
             + m0.z*(m0.z-tq[0].z) + m0.w*(m0.w-tq[0].w)
             + m1.x*(m1.x-tq[1].x) + m1.y*(m1.y-tq[1].y)
             + m1.z*(m1.z-tq[1].z) + m1.w*(m1.w-tq[1].w);
    float sB = m2.x*(m2.x-tq[2].x) + m2.y*(m2.y-tq[2].y)
             + m2.z*(m2.z-tq[2].z) + m2.w*(m2.w-tq[2].w)
             + m3.x*(m3.x-tq[3].x) + m3.y*(m3.y-tq[3].y)
             + m3.z*(m3.z-tq[3].z) + m3.w*(m3.w-tq[3].w);
    float s = sA + sB;
    s += __shfl_xor(s, 1);
    s += __shfl_xor(s, 2);
    s += __shfl_xor(s, 4);        // lanes ln==0 hold full row score

    if (ln == 0) {                // 8 active lanes, one row each
      const int m = waveBase + i * 8 + g;
      bool skip = false;
      #pragma unroll
      for (int r = 0; r < RD; ++r) skip |= (m == rp[r]);  // scattered rows: stale
      if (!skip && (s < bv[7] || (s == bv[7] && m < bi[7]))) TOP8_INSERT(bv, bi, s, m);
    }
  }

  // Merge 32 group-top8s (4 waves x 8 groups) -> chunk top8.
  __shared__ float lv[32][8];
  __shared__ int   li[32][8];
  if (ln == 0) {
    #pragma unroll
    for (int j = 0; j < 8; ++j) { lv[w * 8 + g][j] = bv[j]; li[w * 8 + g][j] = bi[j]; }
  }
  __syncthreads();
  for (int s = 16; s >= 1; s >>= 1) {
    if (t < s) {
      float mv[8]; int mi[8];
      #pragma unroll
      for (int j = 0; j < 8; ++j) { mv[j] = lv[t][j]; mi[j] = li[t][j]; }
      #pragma unroll
      for (int j = 0; j < 8; ++j) {
        float v = lv[t + s][j]; int i = li[t + s][j];
        if (v < mv[7] || (v == mv[7] && i < mi[7])) TOP8_INSERT(mv, mi, v, i);
      }
      #pragma unroll
      for (int j = 0; j < 8; ++j) { lv[t][j] = mv[j]; li[t][j] = mi[j]; }
    }
    __syncthreads();
  }
  if (t < 8) {
    cand_val[b * CAND_PER_BATCH + chunk * 8 + t] = lv[0][t];
    cand_idx[b * CAND_PER_BATCH + chunk * 8 + t] = li[0][t];
  }
}

__global__ __launch_bounds__(128)
void final_kernel(const float* __restrict__ cand_val, const int* __restrict__ cand_idx,
                  const float* __restrict__ memory, const float* __restrict__ new_rv,
                  const int* __restrict__ rpos, float* __restrict__ out) {
  const int b = blockIdx.x, t = threadIdx.x;  // 128
  __shared__ float lv[128][8];
  __shared__ int   li[128][8];
  __shared__ int   posS[KSEL], srcS[KSEL];

  float bv[8]; int bi[8];
  #pragma unroll
  for (int j = 0; j < 8; ++j) { bv[j] = FLT_MAX; bi[j] = INT_MAX; }

  for (int e = t; e < CAND_REAL; e += 128) {
    float v = cand_val[b * CAND_PER_BATCH + e];
    int   i = cand_idx[b * CAND_PER_BATCH + e];
    if (v < bv[7] || (v == bv[7] && i < bi[7])) TOP8_INSERT(bv, bi, v, i);
  }
  #pragma unroll
  for (int j = 0; j < 8; ++j) { lv[t][j] = bv[j]; li[t][j] = bi[j]; }
  __syncthreads();

  for (int stride = 64; stride >= 1; stride >>= 1) {
    if (t < stride) {
      #pragma unroll
      for (int j = 0; j < 8; ++j) {
        float v = lv[t + stride][j]; int i = li[t + stride][j];
        if (v < bv[7] || (v == bv[7] && i < bi[7])) TOP8_INSERT(bv, bi, v, i);
      }
      #pragma unroll
      for (int j = 0; j < 8; ++j) { lv[t][j] = bv[j]; li[t][j] = bi[j]; }
    }
    __syncthreads();
  }

  if (t < KSEL) {
    int p = li[0][t];
    int src = -1;
    for (int r = 0; r < RD; ++r) if (rpos[b * RD + r] == p) src = r;  // last wins
    posS[t] = p; srcS[t] = src;
  }
  __syncthreads();

  for (int e = t; e < KSEL * WD; e += 128) {
    int k = e >> 7, wv = e & 127;
    int p = posS[k], src = srcS[k];
    float val = (src >= 0) ? new_rv[(b * RD + src) * WD + wv]
                           : memory[((size_t)b * MEMN + p) * WD + wv];
    out[b * KSEL * WD + e] = val;
  }
}

extern "C" void kernel_launch(void* const* d_in, const int* in_sizes, int n_in,
                              void* d_out, int out_size, void* d_ws, size_t ws_size,
                              hipStream_t stream) {
  const float* x      = (const float*)d_in[0];
  const float* Wif    = (const float*)d_in[1];
  const float* bif    = (const float*)d_in[2];
  const float* memory = (const float*)d_in[3];
  const float* rw     = (const float*)d_in[4];
  const float* rv     = (const float*)d_in[5];
  const int*   rpos   = (const int*)d_in[6];
  // d_in[7] (last_used_mem) unused: reference drops that gathered row.

  float* ws       = (float*)d_ws;
  float* xi_part  = ws;                                   // BD*KSEG*XI_STRIDE floats
  float* xi       = xi_part + BD * KSEG * XI_STRIDE;      // BD*XI_STRIDE
  float* new_rv   = xi + BD * XI_STRIDE;                  // BD*RD*WD
  float* cand_val = new_rv + BD * RD * WD;                // BD*CAND_PER_BATCH
  int*   cand_idx = (int*)(cand_val + BD * CAND_PER_BATCH);
  float* out      = (float*)d_out;

  xi_part_kernel<<<dim3(BD, KSEG), dim3(288), 0, stream>>>(x, Wif, xi_part);
  head_kernel<<<dim3(BD), dim3(320), 0, stream>>>(xi_part, bif, rw, rv, rpos,
                                                  xi, new_rv, cand_val, cand_idx);
  scan_kernel<<<dim3(NCHUNK, BD), dim3(256), 0, stream>>>(memory, xi, rpos, cand_val, cand_idx);
  final_kernel<<<dim3(BD), dim3(128), 0, stream>>>(cand_val, cand_idx, memory, new_rv, rpos, out);
}

// Round 8
// 215.604 us; speedup vs baseline: 1.1781x; 1.0564x over previous
//
#include <hip/hip_runtime.h>
#include <float.h>
#include <limits.h>

#define MEMN 65536
#define WD 128
#define KSEL 8
#define RD 9
#define BD 32
#define IND 512
#define IFACE 266
#define XI_STRIDE 272   // pad 266 -> 272 floats (1088B, 16B-aligned rows)

#define KSEG 8
#define KSEG_LEN (IND / KSEG)            // 64

#define NCHUNK 64
#define ROWS_PER_CHUNK 1024              // per block; 4 waves x 256 rows
#define CAND_SCAN (NCHUNK * KSEL)        // 512
#define CAND_REAL (CAND_SCAN + RD)       // 521
#define CAND_PER_BATCH 528               // padded

typedef float fvec4 __attribute__((ext_vector_type(4)));

// Sorted ascending (val, idx) top-8 insert; fully unrolled -> registers only.
#define TOP8_INSERT(bv, bi, vin, iin)                                  \
  { float _v = (vin); int _i = (iin);                                  \
    _Pragma("unroll")                                                  \
    for (int _j = 0; _j < 8; ++_j) {                                   \
      bool _b = (_v < bv[_j]) || (_v == bv[_j] && _i < bi[_j]);        \
      float _tv = bv[_j]; int _ti = bi[_j];                            \
      bv[_j] = _b ? _v : _tv;  bi[_j] = _b ? _i : _ti;                 \
      _v = _b ? _tv : _v;      _i = _b ? _ti : _i;                     \
    } }

__device__ __forceinline__ fvec4 ntload(const void* p) {
  return __builtin_nontemporal_load((const fvec4*)p);
}

// Split-K partial GEMM: block (b, seg) computes 64-deep partials for all 266 cols.
__global__ __launch_bounds__(288)
void xi_part_kernel(const float* __restrict__ x, const float* __restrict__ Wif,
                    float* __restrict__ xi_part) {
  const int b = blockIdx.x, seg = blockIdx.y, c = threadIdx.x;
  if (c >= IFACE) return;
  const float* xr = x + b * IND + seg * KSEG_LEN;       // block-uniform -> s_loads
  const float* wp = Wif + (size_t)(seg * KSEG_LEN) * IFACE + c;
  float a0 = 0.f, a1 = 0.f, a2 = 0.f, a3 = 0.f;
  #pragma unroll
  for (int k = 0; k < KSEG_LEN; k += 4) {
    a0 += xr[k]     * wp[(size_t)k * IFACE];
    a1 += xr[k + 1] * wp[(size_t)(k + 1) * IFACE];
    a2 += xr[k + 2] * wp[(size_t)(k + 2) * IFACE];
    a3 += xr[k + 3] * wp[(size_t)(k + 3) * IFACE];
  }
  xi_part[(b * KSEG + seg) * XI_STRIDE + c] = (a0 + a1) + (a2 + a3);
}

// Fused: xi reduce (+bias) -> gates/new_rv -> fixup candidate scores.
__global__ __launch_bounds__(320)
void head_kernel(const float* __restrict__ xi_part, const float* __restrict__ bif,
                 const float* __restrict__ read_weights, const float* __restrict__ read_vectors,
                 const int* __restrict__ rpos,
                 float* __restrict__ xi, float* __restrict__ new_rv,
                 float* __restrict__ cand_val, int* __restrict__ cand_idx) {
  const int b = blockIdx.x, t = threadIdx.x;  // 320
  __shared__ float xiS[IFACE];
  __shared__ float wwS[RD];
  __shared__ float nvS[RD][WD];

  // phase 0: reduce split-K partials
  if (t < IFACE) {
    float acc = bif[t];
    #pragma unroll
    for (int s = 0; s < KSEG; ++s)
      acc += xi_part[(b * KSEG + s) * XI_STRIDE + t];
    xiS[t] = acc;
    xi[b * XI_STRIDE + t] = acc;   // scan reads query cols [0,128)
  }
  __syncthreads();

  // phase 1: write weights
  if (t < RD) {
    float g  = 1.f / (1.f + __expf(-xiS[2 * WD + t]));
    float wg = 1.f / (1.f + __expf(-xiS[IFACE - 1]));
    wwS[t] = wg * (g * read_weights[b * RD + t] + (1.f - g));
  }
  __syncthreads();

  // phase 2: new_rv
  if (t < WD) {
    const float wv = xiS[WD + t];
    #pragma unroll
    for (int r = 0; r < RD; ++r) {
      float nv = read_vectors[(b * RD + r) * WD + t] + wwS[r] * wv;
      nvS[r][t] = nv;
      new_rv[(b * RD + r) * WD + t] = nv;
    }
  }
  __syncthreads();

  // phase 3: fixup scores for the 9 scattered rows (wave 0 only)
  if (t < 64) {
    const int lane = t;
    const float q0 = xiS[lane * 2], q1 = xiS[lane * 2 + 1];
    for (int r = 0; r < RD; ++r) {
      float m0 = nvS[r][lane * 2], m1 = nvS[r][lane * 2 + 1];
      float s = m0 * (m0 - 2.f * q0) + m1 * (m1 - 2.f * q1);
      #pragma unroll
      for (int off = 32; off; off >>= 1) s += __shfl_xor(s, off);
      if (lane == 0) {
        int p = rpos[b * RD + r];
        bool dup = false;
        for (int r2 = r + 1; r2 < RD; ++r2) dup |= (rpos[b * RD + r2] == p);
        int slot = b * CAND_PER_BATCH + CAND_SCAN + r;
        cand_val[slot] = dup ? FLT_MAX : s;   // numpy scatter: last duplicate wins
        cand_idx[slot] = dup ? INT_MAX : p;
      }
    }
  }
}

// 256 threads = 4 waves; wave handles 4 rows/iter via 16-lane groups.
// Lane ln of group g reads bytes ln*16 + j*256 (j=0,1) of row (base + i*4 + g):
// each row is fetched as TWO CONSECUTIVE 128B lines (256B contiguous per
// group). R6->R7 (64B->128B contiguous per row) gave +13us; this continues
// the same axis 128B->256B with everything else held equal (nt kept,
// unroll 4 keeps 8 loads in flight per lane like R7).
__global__ __launch_bounds__(256)
void scan_kernel(const float* __restrict__ memory, const float* __restrict__ xi,
                 const int* __restrict__ rpos,
                 float* __restrict__ cand_val, int* __restrict__ cand_idx) {
  const int b = blockIdx.y, chunk = blockIdx.x;
  const int t = threadIdx.x;
  const int w = t >> 6, l = t & 63, g = l >> 4, ln = l & 15;
  const int waveBase = chunk * ROWS_PER_CHUNK + w * (ROWS_PER_CHUNK / 4);

  int rp[RD];
  #pragma unroll
  for (int r = 0; r < RD; ++r) rp[r] = rpos[b * RD + r];

  // 2*query, this lane's 8 columns (2 vec4s): cols ln*4 + j*64
  fvec4 tq[2];
  #pragma unroll
  for (int j = 0; j < 2; ++j) {
    fvec4 q = *(const fvec4*)(xi + b * XI_STRIDE + j * 64 + ln * 4);
    tq[j] = q * 2.f;
  }

  float bv[8]; int bi[8];
  #pragma unroll
  for (int j = 0; j < 8; ++j) { bv[j] = FLT_MAX; bi[j] = INT_MAX; }

  const char* base = (const char*)memory + (size_t)b * MEMN * (WD * 4)
                   + (size_t)(waveBase + g) * (WD * 4) + ln * 16;

  #pragma unroll 4
  for (int i = 0; i < ROWS_PER_CHUNK / 4 / 4; ++i) {    // 64 iters, 4 rows each
    const char* p = base + (size_t)i * 2048;
    const fvec4 m0 = ntload(p);
    const fvec4 m1 = ntload(p + 256);

    float s = m0.x*(m0.x-tq[0].x) + m0.y*(m0.y-tq[0].y)
            + m0.z*(m0.z-tq[0].z) + m0.w*(m0.w-tq[0].w)
            + m1.x*(m1.x-tq[1].x) + m1.y*(m1.y-tq[1].y)
            + m1.z*(m1.z-tq[1].z) + m1.w*(m1.w-tq[1].w);
    s += __shfl_xor(s, 1);
    s += __shfl_xor(s, 2);
    s += __shfl_xor(s, 4);
    s += __shfl_xor(s, 8);        // lanes ln==0 hold full row score

    if (ln == 0) {                // 4 active lanes, one row each
      const int m = waveBase + i * 4 + g;
      bool skip = false;
      #pragma unroll
      for (int r = 0; r < RD; ++r) skip |= (m == rp[r]);  // scattered rows: stale
      if (!skip && (s < bv[7] || (s == bv[7] && m < bi[7]))) TOP8_INSERT(bv, bi, s, m);
    }
  }

  // Merge 16 group-top8s (4 waves x 4 groups) -> chunk top8.
  __shared__ float lv[16][8];
  __shared__ int   li[16][8];
  if (ln == 0) {
    #pragma unroll
    for (int j = 0; j < 8; ++j) { lv[w * 4 + g][j] = bv[j]; li[w * 4 + g][j] = bi[j]; }
  }
  __syncthreads();
  for (int s = 8; s >= 1; s >>= 1) {
    if (t < s) {
      float mv[8]; int mi[8];
      #pragma unroll
      for (int j = 0; j < 8; ++j) { mv[j] = lv[t][j]; mi[j] = li[t][j]; }
      #pragma unroll
      for (int j = 0; j < 8; ++j) {
        float v = lv[t + s][j]; int i = li[t + s][j];
        if (v < mv[7] || (v == mv[7] && i < mi[7])) TOP8_INSERT(mv, mi, v, i);
      }
      #pragma unroll
      for (int j = 0; j < 8; ++j) { lv[t][j] = mv[j]; li[t][j] = mi[j]; }
    }
    __syncthreads();
  }
  if (t < 8) {
    cand_val[b * CAND_PER_BATCH + chunk * 8 + t] = lv[0][t];
    cand_idx[b * CAND_PER_BATCH + chunk * 8 + t] = li[0][t];
  }
}

__global__ __launch_bounds__(128)
void final_kernel(const float* __restrict__ cand_val, const int* __restrict__ cand_idx,
                  const float* __restrict__ memory, const float* __restrict__ new_rv,
                  const int* __restrict__ rpos, float* __restrict__ out) {
  const int b = blockIdx.x, t = threadIdx.x;  // 128
  __shared__ float lv[128][8];
  __shared__ int   li[128][8];
  __shared__ int   posS[KSEL], srcS[KSEL];

  float bv[8]; int bi[8];
  #pragma unroll
  for (int j = 0; j < 8; ++j) { bv[j] = FLT_MAX; bi[j] = INT_MAX; }

  for (int e = t; e < CAND_REAL; e += 128) {
    float v = cand_val[b * CAND_PER_BATCH + e];
    int   i = cand_idx[b * CAND_PER_BATCH + e];
    if (v < bv[7] || (v == bv[7] && i < bi[7])) TOP8_INSERT(bv, bi, v, i);
  }
  #pragma unroll
  for (int j = 0; j < 8; ++j) { lv[t][j] = bv[j]; li[t][j] = bi[j]; }
  __syncthreads();

  for (int stride = 64; stride >= 1; stride >>= 1) {
    if (t < stride) {
      #pragma unroll
      for (int j = 0; j < 8; ++j) {
        float v = lv[t + stride][j]; int i = li[t + stride][j];
        if (v < bv[7] || (v == bv[7] && i < bi[7])) TOP8_INSERT(bv, bi, v, i);
      }
      #pragma unroll
      for (int j = 0; j < 8; ++j) { lv[t][j] = bv[j]; li[t][j] = bi[j]; }
    }
    __syncthreads();
  }

  if (t < KSEL) {
    int p = li[0][t];
    int src = -1;
    for (int r = 0; r < RD; ++r) if (rpos[b * RD + r] == p) src = r;  // last wins
    posS[t] = p; srcS[t] = src;
  }
  __syncthreads();

  for (int e = t; e < KSEL * WD; e += 128) {
    int k = e >> 7, wv = e & 127;
    int p = posS[k], src = srcS[k];
    float val = (src >= 0) ? new_rv[(b * RD + src) * WD + wv]
                           : memory[((size_t)b * MEMN + p) * WD + wv];
    out[b * KSEL * WD + e] = val;
  }
}

extern "C" void kernel_launch(void* const* d_in, const int* in_sizes, int n_in,
                              void* d_out, int out_size, void* d_ws, size_t ws_size,
                              hipStream_t stream) {
  const float* x      = (const float*)d_in[0];
  const float* Wif    = (const float*)d_in[1];
  const float* bif    = (const float*)d_in[2];
  const float* memory = (const float*)d_in[3];
  const float* rw     = (const float*)d_in[4];
  const float* rv     = (const float*)d_in[5];
  const int*   rpos   = (const int*)d_in[6];
  // d_in[7] (last_used_mem) unused: reference drops that gathered row.

  float* ws       = (float*)d_ws;
  float* xi_part  = ws;                                   // BD*KSEG*XI_STRIDE floats
  float* xi       = xi_part + BD * KSEG * XI_STRIDE;      // BD*XI_STRIDE
  float* new_rv   = xi + BD * XI_STRIDE;                  // BD*RD*WD
  float* cand_val = new_rv + BD * RD * WD;                // BD*CAND_PER_BATCH
  int*   cand_idx = (int*)(cand_val + BD * CAND_PER_BATCH);
  float* out      = (float*)d_out;

  xi_part_kernel<<<dim3(BD, KSEG), dim3(288), 0, stream>>>(x, Wif, xi_part);
  head_kernel<<<dim3(BD), dim3(320), 0, stream>>>(xi_part, bif, rw, rv, rpos,
                                                  xi, new_rv, cand_val, cand_idx);
  scan_kernel<<<dim3(NCHUNK, BD), dim3(256), 0, stream>>>(memory, xi, rpos, cand_val, cand_idx);
  final_kernel<<<dim3(BD), dim3(128), 0, stream>>>(cand_val, cand_idx, memory, new_rv, rpos, out);
}